// Round 1
// baseline (718.499 us; speedup 1.0000x reference)
//
#include <hip/hip_runtime.h>
#include <cstdint>
#include <cstddef>

// ---- problem constants ----
static constexpr int CB   = 16;    // batch
static constexpr int CL   = 512;   // input seq len
static constexpr int CN   = 321;   // variates
static constexpr int CMK  = 4;     // mark features
static constexpr int CT   = CN + CMK;  // 325 tokens
static constexpr int CD   = 512;   // d_model
static constexpr int CS   = 16;    // state dim
static constexpr int CDTR = 32;    // dt rank
static constexpr int CPRED= 96;    // horizon
static constexpr int CM   = CB * CT;   // 5200 rows

enum GMode { M_EMBED=0, M_PLAIN=1, M_DT=2, M_Z=3, M_WO=4, M_PROJ=5 };

__device__ __forceinline__ float softplus_f(float x) {
    return fmaxf(x, 0.f) + log1pf(__expf(-fabsf(x)));
}

// ---------------- stats: mean / stdev over L per (b, n) ----------------
__global__ __launch_bounds__(256) void stats_k(const float* __restrict__ x,
                                               float* __restrict__ means,
                                               float* __restrict__ stdev)
{
    const int b = blockIdx.x;
    const int n = blockIdx.y * 256 + threadIdx.x;
    if (n >= CN) return;
    float s = 0.f, ss = 0.f;
    for (int l = 0; l < CL; ++l) {
        const float v = x[((size_t)b * CL + l) * CN + n];
        s += v; ss += v * v;
    }
    const float mu  = s / CL;
    const float var = ss / CL - mu * mu;
    means[b * CN + n] = mu;
    stdev[b * CN + n] = sqrtf(var + 1e-5f);
}

// ---------------- generic tiled f32 GEMM, 64x64x16, 4x4 microtile ----------------
// C[M x Nmat] = A[M x K] @ B[K x Nmat] (+bias) with mode-specific A-source/epilogue.
template<int MODE>
__global__ __launch_bounds__(256) void gemm_k(
    const float* __restrict__ A, int lda,
    const float* __restrict__ Bm, int ldb,
    int M, int Nmat, int K,
    const float* __restrict__ bias,
    float* __restrict__ C,
    const float* __restrict__ X1,
    const float* __restrict__ X2,
    const float* __restrict__ X3,
    const float* __restrict__ X4)
{
    __shared__ float As[16][68];   // [k][m], stride 68: float4-aligned, 2-way bank alias only
    __shared__ float Bs[16][64];   // [k][n]

    const int tid = threadIdx.x;
    const int bm = blockIdx.x * 64;
    const int bn = blockIdx.y * 64;

    const int arr = tid & 63;            // A row within tile
    const int ak0 = (tid >> 6) << 2;     // A k offset: 0/4/8/12
    const int r   = bm + arr;

    const int bkr = tid >> 4;            // B k row 0..15
    const int bn0 = (tid & 15) << 2;     // B col offset

    const int tm0 = (tid >> 4) << 2;     // microtile row base
    const int tn0 = (tid & 15) << 2;     // microtile col base

    // EMBED: per-row normalization params
    int eb = 0, et = 0; bool isx = false; float mean_ = 0.f, rstd_ = 1.f;
    if constexpr (MODE == M_EMBED) {
        if (r < M) {
            eb = r / CT; et = r % CT; isx = (et < CN);
            if (isx) { mean_ = X3[eb * CN + et]; rstd_ = 1.0f / X4[eb * CN + et]; }
        }
    }

    float acc[4][4] = {};

    for (int k0 = 0; k0 < K; k0 += 16) {
        float av[4];
        if constexpr (MODE == M_EMBED) {
            #pragma unroll
            for (int i = 0; i < 4; ++i) {
                const int l = k0 + ak0 + i;
                float v = 0.f;
                if (r < M) {
                    if (isx) v = (X1[((size_t)eb * CL + l) * CN + et] - mean_) * rstd_;
                    else     v = X2[((size_t)eb * CL + l) * CMK + (et - CN)];
                }
                av[i] = v;
            }
        } else if constexpr (MODE == M_Z) {
            #pragma unroll
            for (int i = 0; i < 4; ++i) {
                const int kk = k0 + ak0 + i;
                av[i] = (r < M) ? (kk < CD ? X1[(size_t)r * CD + kk]
                                          : X2[(size_t)r * CD + kk - CD]) : 0.f;
            }
        } else {
            if (r < M) {
                const float4 t4 = *reinterpret_cast<const float4*>(&A[(size_t)r * lda + k0 + ak0]);
                av[0] = t4.x; av[1] = t4.y; av[2] = t4.z; av[3] = t4.w;
            } else { av[0] = av[1] = av[2] = av[3] = 0.f; }
        }
        float4 bv = make_float4(0.f, 0.f, 0.f, 0.f);
        if (bn + bn0 < Nmat)
            bv = *reinterpret_cast<const float4*>(&Bm[(size_t)(k0 + bkr) * ldb + bn + bn0]);

        __syncthreads();
        #pragma unroll
        for (int i = 0; i < 4; ++i) As[ak0 + i][arr] = av[i];
        *reinterpret_cast<float4*>(&Bs[bkr][bn0]) = bv;
        __syncthreads();

        #pragma unroll
        for (int kk = 0; kk < 16; ++kk) {
            const float4 a4 = *reinterpret_cast<const float4*>(&As[kk][tm0]);
            const float4 b4 = *reinterpret_cast<const float4*>(&Bs[kk][tn0]);
            const float aa[4] = {a4.x, a4.y, a4.z, a4.w};
            const float bb[4] = {b4.x, b4.y, b4.z, b4.w};
            #pragma unroll
            for (int i = 0; i < 4; ++i)
                #pragma unroll
                for (int j = 0; j < 4; ++j)
                    acc[i][j] = fmaf(aa[i], bb[j], acc[i][j]);
        }
    }

    // ---- epilogue ----
    #pragma unroll
    for (int i = 0; i < 4; ++i) {
        const int rr = bm + tm0 + i;
        if (rr >= M) continue;
        int pb = 0, pt = 0; float sc = 1.f, sh = 0.f;
        if constexpr (MODE == M_PROJ) {
            pb = rr / CT; pt = rr % CT;
            if (pt >= CN) continue;
            sc = X1[pb * CN + pt]; sh = X2[pb * CN + pt];
        }
        #pragma unroll
        for (int j = 0; j < 4; ++j) {
            const int cc = bn + tn0 + j;
            if (cc >= Nmat) continue;
            float v = acc[i][j];
            if (bias) v += bias[cc];
            if constexpr (MODE == M_DT) {
                v = softplus_f(v);
            }
            if constexpr (MODE == M_Z) {
                const float z = 1.f / (1.f + __expf(-v));
                const float a1 = X1[(size_t)rr * CD + cc];   // yf
                const float b1 = X2[(size_t)rr * CD + cc];   // yb
                v = z * a1 + (1.f - z) * b1;
            }
            if constexpr (MODE == M_WO) {
                v += X1[(size_t)rr * CD + cc];               // enc residual
            }
            if constexpr (MODE == M_PROJ) {
                C[(size_t)pb * (CPRED * CN) + (size_t)cc * CN + pt] = v * sc + sh;
            } else {
                C[(size_t)rr * Nmat + cc] = v;
            }
        }
    }
}

// ---------------- selective scan (both directions) ----------------
// one thread per (b, dir, d); S=16 states in registers; T=325 sequential.
__global__ __launch_bounds__(64) void scan_k(
    const float* __restrict__ enc,
    const float* __restrict__ xzf, const float* __restrict__ xzb,
    const float* __restrict__ dtf, const float* __restrict__ dtb,
    const float* __restrict__ Alogf, const float* __restrict__ Alogb,
    const float* __restrict__ Dskf, const float* __restrict__ Dskb,
    float* __restrict__ yf, float* __restrict__ yb)
{
    const int b   = blockIdx.x;
    const int dir = blockIdx.y;
    const int dd  = blockIdx.z * 64 + threadIdx.x;

    const float* __restrict__ xz   = dir ? xzb : xzf;
    const float* __restrict__ dt   = dir ? dtb : dtf;
    const float* __restrict__ Alog = dir ? Alogb : Alogf;
    const float dsk = (dir ? Dskb : Dskf)[dd];
    float* __restrict__ y = dir ? yb : yf;

    float a[CS], h[CS];
    #pragma unroll
    for (int s = 0; s < CS; ++s) { a[s] = -__expf(Alog[dd * CS + s]); h[s] = 0.f; }

    __shared__ float sBC[32];   // Bc[0:16], Cc[16:32]

    for (int step = 0; step < CT; ++step) {
        const int t = dir ? (CT - 1 - step) : step;
        const size_t r = (size_t)b * CT + t;
        __syncthreads();
        if (threadIdx.x < 32) sBC[threadIdx.x] = xz[r * 64 + 32 + threadIdx.x];
        __syncthreads();
        const float dtv = dt[r * CD + dd];
        const float u   = enc[r * CD + dd];
        const float du  = dtv * u;
        float acc = 0.f;
        #pragma unroll
        for (int s = 0; s < CS; ++s) {
            h[s] = __expf(dtv * a[s]) * h[s] + du * sBC[s];
            acc  = fmaf(h[s], sBC[16 + s], acc);
        }
        y[r * CD + dd] = fmaf(u, dsk, acc);
    }
}

// ---------------- rowwise LayerNorm over D=512, in place ----------------
__global__ __launch_bounds__(256) void ln_k(float* __restrict__ h,
                                            const float* __restrict__ g,
                                            const float* __restrict__ be)
{
    const size_t r = blockIdx.x;
    const int tid = threadIdx.x;
    float2 v = *reinterpret_cast<float2*>(&h[r * CD + tid * 2]);
    float s  = v.x + v.y;
    float ss = v.x * v.x + v.y * v.y;
    #pragma unroll
    for (int o = 32; o; o >>= 1) { s += __shfl_down(s, o); ss += __shfl_down(ss, o); }
    __shared__ float red[10];
    const int w = tid >> 6;
    if ((tid & 63) == 0) { red[w] = s; red[4 + w] = ss; }
    __syncthreads();
    if (tid == 0) {
        const float S1 = red[0] + red[1] + red[2] + red[3];
        const float S2 = red[4] + red[5] + red[6] + red[7];
        const float mu = S1 / CD;
        red[8] = mu;
        red[9] = rsqrtf(S2 / CD - mu * mu + 1e-5f);
    }
    __syncthreads();
    const float mu = red[8], rs = red[9];
    v.x = (v.x - mu) * rs * g[tid * 2]     + be[tid * 2];
    v.y = (v.y - mu) * rs * g[tid * 2 + 1] + be[tid * 2 + 1];
    *reinterpret_cast<float2*>(&h[r * CD + tid * 2]) = v;
}

extern "C" void kernel_launch(void* const* d_in, const int* in_sizes, int n_in,
                              void* d_out, int out_size, void* d_ws, size_t ws_size,
                              hipStream_t stream)
{
    const float* x_enc  = (const float*)d_in[0];
    const float* x_mark = (const float*)d_in[1];
    const float* W_emb  = (const float*)d_in[4];
    const float* b_emb  = (const float*)d_in[5];
    const float* Alogf  = (const float*)d_in[6];
    const float* Wxf    = (const float*)d_in[7];
    const float* Wdtf   = (const float*)d_in[8];
    const float* bdtf   = (const float*)d_in[9];
    const float* Dskf   = (const float*)d_in[10];
    const float* Alogb  = (const float*)d_in[11];
    const float* Wxb    = (const float*)d_in[12];
    const float* Wdtb   = (const float*)d_in[13];
    const float* bdtb   = (const float*)d_in[14];
    const float* Dskb   = (const float*)d_in[15];
    const float* Wz     = (const float*)d_in[16];
    const float* bz     = (const float*)d_in[17];
    const float* Wo     = (const float*)d_in[18];
    const float* bo     = (const float*)d_in[19];
    const float* lng    = (const float*)d_in[20];
    const float* lnb    = (const float*)d_in[21];
    const float* Wproj  = (const float*)d_in[22];
    const float* bproj  = (const float*)d_in[23];
    float* out = (float*)d_out;

    float* ws    = (float*)d_ws;
    float* means = ws;                       // 5136
    float* stdev = means + 5136;             // 5136
    float* enc   = stdev + 5136;             // 2662400
    float* xzf   = enc   + 2662400;          // 332800
    float* xzb   = xzf   + 332800;           // 332800
    float* dtf   = xzb   + 332800;           // 2662400
    float* dtb   = dtf   + 2662400;          // 2662400
    float* yfb   = dtb   + 2662400;          // 2662400
    float* ybb   = yfb   + 2662400;          // 2662400
    float* fused = dtf;                      // alias: dt dead after scan
    float* hb    = dtb;                      // alias

    stats_k<<<dim3(16, 2), 256, 0, stream>>>(x_enc, means, stdev);

    gemm_k<M_EMBED><<<dim3(82, 8), 256, 0, stream>>>(
        nullptr, 0, W_emb, CD, CM, CD, CL, b_emb, enc, x_enc, x_mark, means, stdev);

    gemm_k<M_PLAIN><<<dim3(82, 1), 256, 0, stream>>>(
        enc, CD, Wxf, 64, CM, 64, CD, nullptr, xzf, nullptr, nullptr, nullptr, nullptr);
    gemm_k<M_PLAIN><<<dim3(82, 1), 256, 0, stream>>>(
        enc, CD, Wxb, 64, CM, 64, CD, nullptr, xzb, nullptr, nullptr, nullptr, nullptr);

    gemm_k<M_DT><<<dim3(82, 8), 256, 0, stream>>>(
        xzf, 64, Wdtf, CD, CM, CD, CDTR, bdtf, dtf, nullptr, nullptr, nullptr, nullptr);
    gemm_k<M_DT><<<dim3(82, 8), 256, 0, stream>>>(
        xzb, 64, Wdtb, CD, CM, CD, CDTR, bdtb, dtb, nullptr, nullptr, nullptr, nullptr);

    scan_k<<<dim3(CB, 2, 8), 64, 0, stream>>>(
        enc, xzf, xzb, dtf, dtb, Alogf, Alogb, Dskf, Dskb, yfb, ybb);

    gemm_k<M_Z><<<dim3(82, 8), 256, 0, stream>>>(
        nullptr, 0, Wz, CD, CM, CD, 2 * CD, bz, fused, yfb, ybb, nullptr, nullptr);

    gemm_k<M_WO><<<dim3(82, 8), 256, 0, stream>>>(
        fused, CD, Wo, CD, CM, CD, CD, bo, hb, enc, nullptr, nullptr, nullptr);

    ln_k<<<CM, 256, 0, stream>>>(hb, lng, lnb);

    gemm_k<M_PROJ><<<dim3(82, 2), 256, 0, stream>>>(
        hb, CD, Wproj, CPRED, CM, CPRED, CD, bproj, out, stdev, means, nullptr, nullptr);
}

// Round 2
// 517.346 us; speedup vs baseline: 1.3888x; 1.3888x over previous
//
#include <hip/hip_runtime.h>
#include <cstdint>
#include <cstddef>

// ---- problem constants ----
static constexpr int CB   = 16;    // batch
static constexpr int CL   = 512;   // input seq len
static constexpr int CN   = 321;   // variates
static constexpr int CMK  = 4;     // mark features
static constexpr int CT   = CN + CMK;  // 325 tokens
static constexpr int CD   = 512;   // d_model
static constexpr int CS   = 16;    // state dim
static constexpr int CDTR = 32;    // dt rank
static constexpr int CPRED= 96;    // horizon
static constexpr int CM   = CB * CT;   // 5200 rows
static constexpr int CH   = 25;    // scan chunk length
static constexpr int CNC  = 13;    // number of chunks (13*25 = 325)

enum GMode { M_EMBED=0, M_PLAIN=1, M_DT=2, M_Z=3, M_WO=4, M_PROJ=5 };

__device__ __forceinline__ float softplus_f(float x) {
    return fmaxf(x, 0.f) + log1pf(__expf(-fabsf(x)));
}

// ---------------- stats: mean / stdev over L per (b, n) ----------------
__global__ __launch_bounds__(256) void stats_k(const float* __restrict__ x,
                                               float* __restrict__ means,
                                               float* __restrict__ stdev)
{
    const int b = blockIdx.x;
    const int n = blockIdx.y * 256 + threadIdx.x;
    if (n >= CN) return;
    float s = 0.f, ss = 0.f;
    for (int l = 0; l < CL; ++l) {
        const float v = x[((size_t)b * CL + l) * CN + n];
        s += v; ss += v * v;
    }
    const float mu  = s / CL;
    const float var = ss / CL - mu * mu;
    means[b * CN + n] = mu;
    stdev[b * CN + n] = sqrtf(var + 1e-5f);
}

// ---------------- generic tiled f32 GEMM, 64x64x16, 4x4 microtile ----------------
template<int MODE>
__global__ __launch_bounds__(256) void gemm_k(
    const float* __restrict__ A, int lda,
    const float* __restrict__ Bm, int ldb,
    int M, int Nmat, int K,
    const float* __restrict__ bias,
    float* __restrict__ C,
    const float* __restrict__ X1,
    const float* __restrict__ X2,
    const float* __restrict__ X3,
    const float* __restrict__ X4)
{
    __shared__ float As[16][68];
    __shared__ float Bs[16][64];

    const int tid = threadIdx.x;
    const int bm = blockIdx.x * 64;
    const int bn = blockIdx.y * 64;

    const int arr = tid & 63;
    const int ak0 = (tid >> 6) << 2;
    const int r   = bm + arr;

    const int bkr = tid >> 4;
    const int bn0 = (tid & 15) << 2;

    const int tm0 = (tid >> 4) << 2;
    const int tn0 = (tid & 15) << 2;

    int eb = 0, et = 0; bool isx = false; float mean_ = 0.f, rstd_ = 1.f;
    if constexpr (MODE == M_EMBED) {
        if (r < M) {
            eb = r / CT; et = r % CT; isx = (et < CN);
            if (isx) { mean_ = X3[eb * CN + et]; rstd_ = 1.0f / X4[eb * CN + et]; }
        }
    }

    float acc[4][4] = {};

    for (int k0 = 0; k0 < K; k0 += 16) {
        float av[4];
        if constexpr (MODE == M_EMBED) {
            #pragma unroll
            for (int i = 0; i < 4; ++i) {
                const int l = k0 + ak0 + i;
                float v = 0.f;
                if (r < M) {
                    if (isx) v = (X1[((size_t)eb * CL + l) * CN + et] - mean_) * rstd_;
                    else     v = X2[((size_t)eb * CL + l) * CMK + (et - CN)];
                }
                av[i] = v;
            }
        } else if constexpr (MODE == M_Z) {
            #pragma unroll
            for (int i = 0; i < 4; ++i) {
                const int kk = k0 + ak0 + i;
                av[i] = (r < M) ? (kk < CD ? X1[(size_t)r * CD + kk]
                                          : X2[(size_t)r * CD + kk - CD]) : 0.f;
            }
        } else {
            if (r < M) {
                const float4 t4 = *reinterpret_cast<const float4*>(&A[(size_t)r * lda + k0 + ak0]);
                av[0] = t4.x; av[1] = t4.y; av[2] = t4.z; av[3] = t4.w;
            } else { av[0] = av[1] = av[2] = av[3] = 0.f; }
        }
        float4 bv = make_float4(0.f, 0.f, 0.f, 0.f);
        if (bn + bn0 < Nmat)
            bv = *reinterpret_cast<const float4*>(&Bm[(size_t)(k0 + bkr) * ldb + bn + bn0]);

        __syncthreads();
        #pragma unroll
        for (int i = 0; i < 4; ++i) As[ak0 + i][arr] = av[i];
        *reinterpret_cast<float4*>(&Bs[bkr][bn0]) = bv;
        __syncthreads();

        #pragma unroll
        for (int kk = 0; kk < 16; ++kk) {
            const float4 a4 = *reinterpret_cast<const float4*>(&As[kk][tm0]);
            const float4 b4 = *reinterpret_cast<const float4*>(&Bs[kk][tn0]);
            const float aa[4] = {a4.x, a4.y, a4.z, a4.w};
            const float bb[4] = {b4.x, b4.y, b4.z, b4.w};
            #pragma unroll
            for (int i = 0; i < 4; ++i)
                #pragma unroll
                for (int j = 0; j < 4; ++j)
                    acc[i][j] = fmaf(aa[i], bb[j], acc[i][j]);
        }
    }

    #pragma unroll
    for (int i = 0; i < 4; ++i) {
        const int rr = bm + tm0 + i;
        if (rr >= M) continue;
        int pb = 0, pt = 0; float sc = 1.f, sh = 0.f;
        if constexpr (MODE == M_PROJ) {
            pb = rr / CT; pt = rr % CT;
            if (pt >= CN) continue;
            sc = X1[pb * CN + pt]; sh = X2[pb * CN + pt];
        }
        #pragma unroll
        for (int j = 0; j < 4; ++j) {
            const int cc = bn + tn0 + j;
            if (cc >= Nmat) continue;
            float v = acc[i][j];
            if (bias) v += bias[cc];
            if constexpr (MODE == M_DT) {
                v = softplus_f(v);
            }
            if constexpr (MODE == M_Z) {
                const float z = 1.f / (1.f + __expf(-v));
                const float a1 = X1[(size_t)rr * CD + cc];
                const float b1 = X2[(size_t)rr * CD + cc];
                v = z * a1 + (1.f - z) * b1;
            }
            if constexpr (MODE == M_WO) {
                v += X1[(size_t)rr * CD + cc];
            }
            if constexpr (MODE == M_PROJ) {
                C[(size_t)pb * (CPRED * CN) + (size_t)cc * CN + pt] = v * sc + sh;
            } else {
                C[(size_t)rr * Nmat + cc] = v;
            }
        }
    }
}

// ---------------- chunked selective scan ----------------
// Pass 1: per (b,dir,chunk,d) scan chunk from h=0 -> Hloc[s], P[s]=prod(dA).
__global__ __launch_bounds__(256) void scan1_k(
    const float* __restrict__ enc,
    const float* __restrict__ xzf, const float* __restrict__ xzb,
    const float* __restrict__ dtf, const float* __restrict__ dtb,
    const float* __restrict__ Alogf, const float* __restrict__ Alogb,
    float* __restrict__ Hloc, float* __restrict__ Pprod)
{
    const int b   = blockIdx.x;
    const int dir = blockIdx.y;
    const int c   = blockIdx.z >> 1;
    const int dd  = (blockIdx.z & 1) * 256 + threadIdx.x;

    const float* __restrict__ xz   = dir ? xzb : xzf;
    const float* __restrict__ dt   = dir ? dtb : dtf;
    const float* __restrict__ Alog = dir ? Alogb : Alogf;

    float a[CS], h[CS], P[CS];
    #pragma unroll
    for (int s = 0; s < CS; ++s) {
        a[s] = -__expf(Alog[dd * CS + s]);
        h[s] = 0.f; P[s] = 1.f;
    }

    __shared__ float sB[CH][CS];
    for (int i = threadIdx.x; i < CH * CS; i += 256) {
        const int st = i >> 4, j = i & 15;
        const int t = dir ? (CT - 1 - (c * CH + st)) : (c * CH + st);
        sB[st][j] = xz[((size_t)b * CT + t) * 64 + 32 + j];
    }
    __syncthreads();

    for (int st = 0; st < CH; ++st) {
        const int t = dir ? (CT - 1 - (c * CH + st)) : (c * CH + st);
        const size_t r = (size_t)b * CT + t;
        const float dtv = dt[r * CD + dd];
        const float du  = dtv * enc[r * CD + dd];
        #pragma unroll
        for (int s = 0; s < CS; ++s) {
            const float da = __expf(dtv * a[s]);
            h[s] = fmaf(da, h[s], du * sB[st][s]);
            P[s] *= da;
        }
    }

    const size_t o = ((((size_t)b * 2 + dir) * CNC + c) * CD + dd) * CS;
    float4* Ho = reinterpret_cast<float4*>(&Hloc[o]);
    float4* Po = reinterpret_cast<float4*>(&Pprod[o]);
    #pragma unroll
    for (int q = 0; q < 4; ++q) {
        Ho[q] = make_float4(h[4*q], h[4*q+1], h[4*q+2], h[4*q+3]);
        Po[q] = make_float4(P[4*q], P[4*q+1], P[4*q+2], P[4*q+3]);
    }
}

// Pass 2: combine chunk states sequentially; overwrite Hloc[c] with the
// state ENTERING chunk c (in place).
__global__ __launch_bounds__(256) void scan2_k(float* __restrict__ Hloc,
                                               const float* __restrict__ Pprod)
{
    const int b   = blockIdx.x;
    const int dir = blockIdx.y;
    const int d   = blockIdx.z * 16 + (threadIdx.x >> 4);
    const int s   = threadIdx.x & 15;
    const size_t base = ((size_t)b * 2 + dir) * CNC * CD * CS + (size_t)d * CS + s;
    float H = 0.f;
    for (int c = 0; c < CNC; ++c) {
        const size_t o = base + (size_t)c * CD * CS;
        const float p  = Pprod[o];
        const float hl = Hloc[o];
        Hloc[o] = H;
        H = fmaf(p, H, hl);
    }
}

// Pass 3: re-scan each chunk from its entry state, producing y.
__global__ __launch_bounds__(256) void scan3_k(
    const float* __restrict__ enc,
    const float* __restrict__ xzf, const float* __restrict__ xzb,
    const float* __restrict__ dtf, const float* __restrict__ dtb,
    const float* __restrict__ Alogf, const float* __restrict__ Alogb,
    const float* __restrict__ Dskf, const float* __restrict__ Dskb,
    const float* __restrict__ Hinit,
    float* __restrict__ yf, float* __restrict__ yb)
{
    const int b   = blockIdx.x;
    const int dir = blockIdx.y;
    const int c   = blockIdx.z >> 1;
    const int dd  = (blockIdx.z & 1) * 256 + threadIdx.x;

    const float* __restrict__ xz   = dir ? xzb : xzf;
    const float* __restrict__ dt   = dir ? dtb : dtf;
    const float* __restrict__ Alog = dir ? Alogb : Alogf;
    const float dsk = (dir ? Dskb : Dskf)[dd];
    float* __restrict__ y = dir ? yb : yf;

    float a[CS], h[CS];
    const size_t o = ((((size_t)b * 2 + dir) * CNC + c) * CD + dd) * CS;
    const float4* Hi = reinterpret_cast<const float4*>(&Hinit[o]);
    #pragma unroll
    for (int q = 0; q < 4; ++q) {
        const float4 v = Hi[q];
        h[4*q] = v.x; h[4*q+1] = v.y; h[4*q+2] = v.z; h[4*q+3] = v.w;
    }
    #pragma unroll
    for (int s = 0; s < CS; ++s) a[s] = -__expf(Alog[dd * CS + s]);

    __shared__ float sB[CH][CS];
    __shared__ float sC[CH][CS];
    for (int i = threadIdx.x; i < 2 * CH * CS; i += 256) {
        const int st = i >> 5, j = i & 31;
        const int t = dir ? (CT - 1 - (c * CH + st)) : (c * CH + st);
        const float v = xz[((size_t)b * CT + t) * 64 + 32 + j];
        if (j < 16) sB[st][j] = v; else sC[st][j - 16] = v;
    }
    __syncthreads();

    for (int st = 0; st < CH; ++st) {
        const int t = dir ? (CT - 1 - (c * CH + st)) : (c * CH + st);
        const size_t r = (size_t)b * CT + t;
        const float dtv = dt[r * CD + dd];
        const float u   = enc[r * CD + dd];
        const float du  = dtv * u;
        float acc = 0.f;
        #pragma unroll
        for (int s = 0; s < CS; ++s) {
            const float da = __expf(dtv * a[s]);
            h[s] = fmaf(da, h[s], du * sB[st][s]);
            acc  = fmaf(h[s], sC[st][s], acc);
        }
        y[r * CD + dd] = fmaf(u, dsk, acc);
    }
}

// ---------------- rowwise LayerNorm over D=512, in place ----------------
__global__ __launch_bounds__(256) void ln_k(float* __restrict__ h,
                                            const float* __restrict__ g,
                                            const float* __restrict__ be)
{
    const size_t r = blockIdx.x;
    const int tid = threadIdx.x;
    float2 v = *reinterpret_cast<float2*>(&h[r * CD + tid * 2]);
    float s  = v.x + v.y;
    float ss = v.x * v.x + v.y * v.y;
    #pragma unroll
    for (int o = 32; o; o >>= 1) { s += __shfl_down(s, o); ss += __shfl_down(ss, o); }
    __shared__ float red[10];
    const int w = tid >> 6;
    if ((tid & 63) == 0) { red[w] = s; red[4 + w] = ss; }
    __syncthreads();
    if (tid == 0) {
        const float S1 = red[0] + red[1] + red[2] + red[3];
        const float S2 = red[4] + red[5] + red[6] + red[7];
        const float mu = S1 / CD;
        red[8] = mu;
        red[9] = rsqrtf(S2 / CD - mu * mu + 1e-5f);
    }
    __syncthreads();
    const float mu = red[8], rs = red[9];
    v.x = (v.x - mu) * rs * g[tid * 2]     + be[tid * 2];
    v.y = (v.y - mu) * rs * g[tid * 2 + 1] + be[tid * 2 + 1];
    *reinterpret_cast<float2*>(&h[r * CD + tid * 2]) = v;
}

extern "C" void kernel_launch(void* const* d_in, const int* in_sizes, int n_in,
                              void* d_out, int out_size, void* d_ws, size_t ws_size,
                              hipStream_t stream)
{
    const float* x_enc  = (const float*)d_in[0];
    const float* x_mark = (const float*)d_in[1];
    const float* W_emb  = (const float*)d_in[4];
    const float* b_emb  = (const float*)d_in[5];
    const float* Alogf  = (const float*)d_in[6];
    const float* Wxf    = (const float*)d_in[7];
    const float* Wdtf   = (const float*)d_in[8];
    const float* bdtf   = (const float*)d_in[9];
    const float* Dskf   = (const float*)d_in[10];
    const float* Alogb  = (const float*)d_in[11];
    const float* Wxb    = (const float*)d_in[12];
    const float* Wdtb   = (const float*)d_in[13];
    const float* bdtb   = (const float*)d_in[14];
    const float* Dskb   = (const float*)d_in[15];
    const float* Wz     = (const float*)d_in[16];
    const float* bz     = (const float*)d_in[17];
    const float* Wo     = (const float*)d_in[18];
    const float* bo     = (const float*)d_in[19];
    const float* lng    = (const float*)d_in[20];
    const float* lnb    = (const float*)d_in[21];
    const float* Wproj  = (const float*)d_in[22];
    const float* bproj  = (const float*)d_in[23];
    float* out = (float*)d_out;

    float* ws    = (float*)d_ws;
    float* means = ws;                       // 5136
    float* stdev = means + 5136;             // 5136
    float* enc   = stdev + 5136;             // 2662400
    float* xzf   = enc   + 2662400;          // 332800
    float* xzb   = xzf   + 332800;           // 332800
    float* dtf   = xzb   + 332800;           // 2662400
    float* dtb   = dtf   + 2662400;          // 2662400
    float* yfb   = dtb   + 2662400;          // 2662400
    float* ybb   = yfb   + 2662400;          // 2662400
    float* Hloc  = ybb   + 2662400;          // 3407872 (16*2*13*512*16)
    float* Pprod = Hloc  + 3407872;          // 3407872
    float* fused = dtf;                      // alias: dt dead after scan
    float* hb    = dtb;                      // alias

    stats_k<<<dim3(16, 2), 256, 0, stream>>>(x_enc, means, stdev);

    gemm_k<M_EMBED><<<dim3(82, 8), 256, 0, stream>>>(
        nullptr, 0, W_emb, CD, CM, CD, CL, b_emb, enc, x_enc, x_mark, means, stdev);

    gemm_k<M_PLAIN><<<dim3(82, 1), 256, 0, stream>>>(
        enc, CD, Wxf, 64, CM, 64, CD, nullptr, xzf, nullptr, nullptr, nullptr, nullptr);
    gemm_k<M_PLAIN><<<dim3(82, 1), 256, 0, stream>>>(
        enc, CD, Wxb, 64, CM, 64, CD, nullptr, xzb, nullptr, nullptr, nullptr, nullptr);

    gemm_k<M_DT><<<dim3(82, 8), 256, 0, stream>>>(
        xzf, 64, Wdtf, CD, CM, CD, CDTR, bdtf, dtf, nullptr, nullptr, nullptr, nullptr);
    gemm_k<M_DT><<<dim3(82, 8), 256, 0, stream>>>(
        xzb, 64, Wdtb, CD, CM, CD, CDTR, bdtb, dtb, nullptr, nullptr, nullptr, nullptr);

    scan1_k<<<dim3(CB, 2, CNC * 2), 256, 0, stream>>>(
        enc, xzf, xzb, dtf, dtb, Alogf, Alogb, Hloc, Pprod);
    scan2_k<<<dim3(CB, 2, 32), 256, 0, stream>>>(Hloc, Pprod);
    scan3_k<<<dim3(CB, 2, CNC * 2), 256, 0, stream>>>(
        enc, xzf, xzb, dtf, dtb, Alogf, Alogb, Dskf, Dskb, Hloc, yfb, ybb);

    gemm_k<M_Z><<<dim3(82, 8), 256, 0, stream>>>(
        nullptr, 0, Wz, CD, CM, CD, 2 * CD, bz, fused, yfb, ybb, nullptr, nullptr);

    gemm_k<M_WO><<<dim3(82, 8), 256, 0, stream>>>(
        fused, CD, Wo, CD, CM, CD, CD, bo, hb, enc, nullptr, nullptr, nullptr);

    ln_k<<<CM, 256, 0, stream>>>(hb, lng, lnb);

    gemm_k<M_PROJ><<<dim3(82, 2), 256, 0, stream>>>(
        hb, CD, Wproj, CPRED, CM, CPRED, CD, bproj, out, stdev, means, nullptr, nullptr);
}

// Round 3
// 333.004 us; speedup vs baseline: 2.1576x; 1.5536x over previous
//
#include <hip/hip_runtime.h>
#include <cstdint>
#include <cstddef>

// ---- problem constants ----
static constexpr int CB   = 16;
static constexpr int CL   = 512;
static constexpr int CN   = 321;
static constexpr int CMK  = 4;
static constexpr int CT   = CN + CMK;  // 325
static constexpr int CD   = 512;
static constexpr int CS   = 16;
static constexpr int CPRED= 96;
static constexpr int CM   = CB * CT;   // 5200
static constexpr int CH   = 25;
static constexpr int CNC  = 13;

typedef short bf16x8 __attribute__((ext_vector_type(8)));
typedef float f32x4  __attribute__((ext_vector_type(4)));

__device__ __forceinline__ float softplus_f(float x) {
    return fmaxf(x, 0.f) + log1pf(__expf(-fabsf(x)));
}
__device__ __forceinline__ short f2bf(float f) {
    uint32_t u = __float_as_uint(f);
    return (short)((u + 0x7fffu + ((u >> 16) & 1u)) >> 16);
}
__device__ __forceinline__ float bf2f(short s) {
    return __uint_as_float(((uint32_t)(uint16_t)s) << 16);
}

// ---------------- stats ----------------
__global__ __launch_bounds__(256) void stats_k(const float* __restrict__ x,
                                               float* __restrict__ means,
                                               float* __restrict__ stdev)
{
    const int b = blockIdx.x;
    const int n = blockIdx.y * 256 + threadIdx.x;
    if (n >= CN) return;
    float s = 0.f, ss = 0.f;
    for (int l = 0; l < CL; ++l) {
        const float v = x[((size_t)b * CL + l) * CN + n];
        s += v; ss += v * v;
    }
    const float mu  = s / CL;
    const float var = ss / CL - mu * mu;
    means[b * CN + n] = mu;
    stdev[b * CN + n] = sqrtf(var + 1e-5f);
}

// ---------------- weight prep: transpose-cast to bf16 [N][K] + Wcomb + biascat ----------------
__global__ __launch_bounds__(256) void wprep_k(
    const float* __restrict__ Wemb, const float* __restrict__ Wxf, const float* __restrict__ Wxb,
    const float* __restrict__ Wdtf, const float* __restrict__ Wdtb,
    const float* __restrict__ Wz,  const float* __restrict__ Wo,  const float* __restrict__ Wproj,
    const float* __restrict__ bdtf, const float* __restrict__ bdtb,
    short* __restrict__ WembT, short* __restrict__ WcatT, short* __restrict__ WzT,
    short* __restrict__ WoT,   short* __restrict__ WpjT,  float* __restrict__ biascat)
{
    const int blk = blockIdx.x;
    const int tid = threadIdx.x;
    if (blk < 1024) {                       // W_emb (512x512) -> WembT[n][k]
        const int e = blk * 256 + tid, n = e >> 9, k = e & 511;
        WembT[(size_t)n * 512 + k] = f2bf(Wemb[(size_t)k * 512 + n]);
    } else if (blk < 1152) {                // Wx_f (512x64) -> WcatT rows 0..63
        const int e = (blk - 1024) * 256 + tid, n = e >> 9, k = e & 511;
        WcatT[(size_t)n * 512 + k] = f2bf(Wxf[(size_t)k * 64 + n]);
    } else if (blk < 1280) {                // Wx_b -> rows 64..127
        const int e = (blk - 1152) * 256 + tid, n = e >> 9, k = e & 511;
        WcatT[(size_t)(64 + n) * 512 + k] = f2bf(Wxb[(size_t)k * 64 + n]);
    } else if (blk < 3328) {                // Wz (1024x512) -> WzT[n][k], K=1024
        const int e = (blk - 1280) * 256 + tid, n = e >> 10, k = e & 1023;
        WzT[(size_t)n * 1024 + k] = f2bf(Wz[(size_t)k * 512 + n]);
    } else if (blk < 4352) {                // Wo (512x512)
        const int e = (blk - 3328) * 256 + tid, n = e >> 9, k = e & 511;
        WoT[(size_t)n * 512 + k] = f2bf(Wo[(size_t)k * 512 + n]);
    } else if (blk < 4544) {                // W_proj (512x96)
        const int e = (blk - 4352) * 256 + tid, n = e >> 9, k = e & 511;
        WpjT[(size_t)n * 512 + k] = f2bf(Wproj[(size_t)k * 96 + n]);
    } else if (blk < 5568) {                // Wcomb_f = Wx_f[:, :32] @ Wdt_f -> rows 128..639
        const int e = (blk - 4544) * 256 + tid, n = e >> 9, k = e & 511;
        float acc = 0.f;
        #pragma unroll
        for (int j = 0; j < 32; ++j) acc = fmaf(Wxf[(size_t)k * 64 + j], Wdtf[(size_t)j * 512 + n], acc);
        WcatT[(size_t)(128 + n) * 512 + k] = f2bf(acc);
    } else if (blk < 6592) {                // Wcomb_b -> rows 640..1151
        const int e = (blk - 5568) * 256 + tid, n = e >> 9, k = e & 511;
        float acc = 0.f;
        #pragma unroll
        for (int j = 0; j < 32; ++j) acc = fmaf(Wxb[(size_t)k * 64 + j], Wdtb[(size_t)j * 512 + n], acc);
        WcatT[(size_t)(640 + n) * 512 + k] = f2bf(acc);
    } else {                                // biascat[1152]
        const int e = (blk - 6592) * 256 + tid;
        if (e < 1152) {
            float v = 0.f;
            if (e >= 640)      v = bdtb[e - 640];
            else if (e >= 128) v = bdtf[e - 128];
            biascat[e] = v;
        }
    }
}

// ---------------- token build: normalize + concat marks, transpose to [b*t][l], bf16 ----------------
__global__ __launch_bounds__(256) void tok_k(const float* __restrict__ xe, const float* __restrict__ xm,
                                             const float* __restrict__ means, const float* __restrict__ stdev,
                                             short* __restrict__ tokbf)
{
    __shared__ float S[64][65];
    const int b = blockIdx.x, l0 = blockIdx.y * 64, t0 = blockIdx.z * 64;
    const int tid = threadIdx.x;
    const int rsub = tid >> 6, c = tid & 63;
    #pragma unroll 4
    for (int i = 0; i < 16; ++i) {
        const int lr = i * 4 + rsub;
        const int t = t0 + c;
        float v = 0.f;
        if (t < CN)      v = xe[((size_t)b * CL + l0 + lr) * CN + t];
        else if (t < CT) v = xm[((size_t)b * CL + l0 + lr) * CMK + (t - CN)];
        S[lr][c] = v;
    }
    __syncthreads();
    #pragma unroll 4
    for (int i = 0; i < 16; ++i) {
        const int tr = i * 4 + rsub;
        const int t = t0 + tr;
        if (t >= CT) continue;
        float v = S[c][tr];
        if (t < CN) v = (v - means[b * CN + t]) / stdev[b * CN + t];
        tokbf[((size_t)b * CT + t) * CL + l0 + c] = f2bf(v);
    }
}

// ---------------- MFMA bf16 GEMM: C = A[MxK] @ Bt[NxK]^T, 128x128 tile, BK=32 ----------------
enum GMode { M_EMBED = 0, M_XZDT = 1, M_Z = 2, M_WO = 3, M_PROJ = 4 };

template<int MODE>
__global__ __launch_bounds__(256) void mgemm_k(
    const short* __restrict__ A, const short* __restrict__ Bt,
    int M, int Nmat, int K,
    const float* __restrict__ bias,
    void* __restrict__ o0, void* __restrict__ o1, void* __restrict__ o2, void* __restrict__ o3,
    const void* __restrict__ a0, const void* __restrict__ a1)
{
    __shared__ short As[4096];   // 128 rows x 32 bf16, XOR-swizzled
    __shared__ short Bs[4096];

    const int tid = threadIdx.x;
    const int bm = blockIdx.x * 128, bn = blockIdx.y * 128;
    const int w = tid >> 6, l = tid & 63;
    const int wm = w >> 1, wn = w & 1;
    const int lr = l & 15, lk = l >> 4;

    f32x4 acc[4][4];
    #pragma unroll
    for (int i = 0; i < 4; ++i)
        #pragma unroll
        for (int j = 0; j < 4; ++j) acc[i][j] = (f32x4){0.f, 0.f, 0.f, 0.f};

    for (int k0 = 0; k0 < K; k0 += 32) {
        __syncthreads();
        #pragma unroll
        for (int q = 0; q < 2; ++q) {
            const int c  = q * 256 + tid;
            const int m  = c >> 2, kc = c & 3;
            const int wi = (m * 32 + kc * 8) ^ ((m & 7) << 3);
            bf16x8 va = {0,0,0,0,0,0,0,0};
            const int gm = bm + m;
            if (gm < M) va = *reinterpret_cast<const bf16x8*>(&A[(size_t)gm * K + k0 + kc * 8]);
            *reinterpret_cast<bf16x8*>(&As[wi]) = va;
            bf16x8 vb = {0,0,0,0,0,0,0,0};
            const int gn = bn + m;
            if (gn < Nmat) vb = *reinterpret_cast<const bf16x8*>(&Bt[(size_t)gn * K + k0 + kc * 8]);
            *reinterpret_cast<bf16x8*>(&Bs[wi]) = vb;
        }
        __syncthreads();

        bf16x8 af[4], bg[4];
        #pragma unroll
        for (int f = 0; f < 4; ++f) {
            const int ar = wm * 64 + f * 16 + lr;
            af[f] = *reinterpret_cast<const bf16x8*>(&As[(ar * 32 + lk * 8) ^ ((ar & 7) << 3)]);
            const int br = wn * 64 + f * 16 + lr;
            bg[f] = *reinterpret_cast<const bf16x8*>(&Bs[(br * 32 + lk * 8) ^ ((br & 7) << 3)]);
        }
        #pragma unroll
        for (int i = 0; i < 4; ++i)
            #pragma unroll
            for (int j = 0; j < 4; ++j)
                acc[i][j] = __builtin_amdgcn_mfma_f32_16x16x32_bf16(af[i], bg[j], acc[i][j], 0, 0, 0);
    }

    // epilogue: C/D layout col = lane&15, row = (lane>>4)*4 + reg
    #pragma unroll
    for (int i = 0; i < 4; ++i) {
        #pragma unroll
        for (int r = 0; r < 4; ++r) {
            const int rr = bm + wm * 64 + i * 16 + lk * 4 + r;
            if (rr >= M) continue;
            #pragma unroll
            for (int j = 0; j < 4; ++j) {
                const int cc = bn + wn * 64 + j * 16 + lr;
                float v = acc[i][j][r];
                if constexpr (MODE == M_EMBED) {
                    v += bias[cc];
                    ((short*)o0)[(size_t)rr * 512 + cc] = f2bf(v);
                } else if constexpr (MODE == M_XZDT) {
                    v += bias[cc];
                    if (cc < 32) { }
                    else if (cc < 64)  ((float*)o0)[(size_t)rr * 32 + cc - 32] = v;
                    else if (cc < 96)  { }
                    else if (cc < 128) ((float*)o1)[(size_t)rr * 32 + cc - 96] = v;
                    else if (cc < 640) ((float*)o2)[(size_t)rr * 512 + cc - 128] = softplus_f(v);
                    else               ((float*)o3)[(size_t)rr * 512 + cc - 640] = softplus_f(v);
                } else if constexpr (MODE == M_Z) {
                    v += bias[cc];
                    const float z  = 1.f / (1.f + __expf(-v));
                    const short* yc = (const short*)a0;
                    const float yf = bf2f(yc[(size_t)rr * 1024 + cc]);
                    const float yb = bf2f(yc[(size_t)rr * 1024 + 512 + cc]);
                    ((short*)o0)[(size_t)rr * 512 + cc] = f2bf(z * yf + (1.f - z) * yb);
                } else if constexpr (MODE == M_WO) {
                    v += bias[cc] + bf2f(((const short*)a0)[(size_t)rr * 512 + cc]);
                    ((float*)o0)[(size_t)rr * 512 + cc] = v;
                } else if constexpr (MODE == M_PROJ) {
                    if (cc >= CPRED) continue;
                    const int pb = rr / CT, pt = rr % CT;
                    if (pt >= CN) continue;
                    v += bias[cc];
                    const float sc = ((const float*)a0)[pb * CN + pt];
                    const float sh = ((const float*)a1)[pb * CN + pt];
                    ((float*)o0)[(size_t)pb * (CPRED * CN) + (size_t)cc * CN + pt] = v * sc + sh;
                }
            }
        }
    }
}

// ---------------- chunked selective scan ----------------
__global__ __launch_bounds__(256) void scan1_k(
    const short* __restrict__ encbf,
    const float* __restrict__ bcf, const float* __restrict__ bcb,
    const float* __restrict__ dtf, const float* __restrict__ dtb,
    const float* __restrict__ Alogf, const float* __restrict__ Alogb,
    float* __restrict__ Hloc, float* __restrict__ Pprod)
{
    const int b   = blockIdx.x;
    const int dir = blockIdx.y;
    const int c   = blockIdx.z >> 1;
    const int dd  = (blockIdx.z & 1) * 256 + threadIdx.x;

    const float* __restrict__ bc   = dir ? bcb : bcf;
    const float* __restrict__ dt   = dir ? dtb : dtf;
    const float* __restrict__ Alog = dir ? Alogb : Alogf;

    float a[CS], h[CS], P[CS];
    #pragma unroll
    for (int s = 0; s < CS; ++s) {
        a[s] = -__expf(Alog[dd * CS + s]);
        h[s] = 0.f; P[s] = 1.f;
    }

    __shared__ float sB[CH][CS];
    for (int i = threadIdx.x; i < CH * CS; i += 256) {
        const int st = i >> 4, j = i & 15;
        const int t = dir ? (CT - 1 - (c * CH + st)) : (c * CH + st);
        sB[st][j] = bc[((size_t)b * CT + t) * 32 + j];
    }
    __syncthreads();

    for (int st = 0; st < CH; ++st) {
        const int t = dir ? (CT - 1 - (c * CH + st)) : (c * CH + st);
        const size_t r = (size_t)b * CT + t;
        const float dtv = dt[r * CD + dd];
        const float du  = dtv * bf2f(encbf[r * CD + dd]);
        #pragma unroll
        for (int s = 0; s < CS; ++s) {
            const float da = __expf(dtv * a[s]);
            h[s] = fmaf(da, h[s], du * sB[st][s]);
            P[s] *= da;
        }
    }

    const size_t o = ((((size_t)b * 2 + dir) * CNC + c) * CD + dd) * CS;
    float4* Ho = reinterpret_cast<float4*>(&Hloc[o]);
    float4* Po = reinterpret_cast<float4*>(&Pprod[o]);
    #pragma unroll
    for (int q = 0; q < 4; ++q) {
        Ho[q] = make_float4(h[4*q], h[4*q+1], h[4*q+2], h[4*q+3]);
        Po[q] = make_float4(P[4*q], P[4*q+1], P[4*q+2], P[4*q+3]);
    }
}

__global__ __launch_bounds__(256) void scan2_k(float* __restrict__ Hloc,
                                               const float* __restrict__ Pprod)
{
    const int b   = blockIdx.x;
    const int dir = blockIdx.y;
    const int d   = blockIdx.z * 16 + (threadIdx.x >> 4);
    const int s   = threadIdx.x & 15;
    const size_t base = ((size_t)b * 2 + dir) * CNC * CD * CS + (size_t)d * CS + s;
    float H = 0.f;
    for (int c = 0; c < CNC; ++c) {
        const size_t o = base + (size_t)c * CD * CS;
        const float p  = Pprod[o];
        const float hl = Hloc[o];
        Hloc[o] = H;
        H = fmaf(p, H, hl);
    }
}

__global__ __launch_bounds__(256) void scan3_k(
    const short* __restrict__ encbf,
    const float* __restrict__ bcf, const float* __restrict__ bcb,
    const float* __restrict__ dtf, const float* __restrict__ dtb,
    const float* __restrict__ Alogf, const float* __restrict__ Alogb,
    const float* __restrict__ Dskf, const float* __restrict__ Dskb,
    const float* __restrict__ Hinit,
    short* __restrict__ ycat)
{
    const int b   = blockIdx.x;
    const int dir = blockIdx.y;
    const int c   = blockIdx.z >> 1;
    const int dd  = (blockIdx.z & 1) * 256 + threadIdx.x;

    const float* __restrict__ bc   = dir ? bcb : bcf;
    const float* __restrict__ dt   = dir ? dtb : dtf;
    const float* __restrict__ Alog = dir ? Alogb : Alogf;
    const float dsk = (dir ? Dskb : Dskf)[dd];

    float a[CS], h[CS];
    const size_t o = ((((size_t)b * 2 + dir) * CNC + c) * CD + dd) * CS;
    const float4* Hi = reinterpret_cast<const float4*>(&Hinit[o]);
    #pragma unroll
    for (int q = 0; q < 4; ++q) {
        const float4 v = Hi[q];
        h[4*q] = v.x; h[4*q+1] = v.y; h[4*q+2] = v.z; h[4*q+3] = v.w;
    }
    #pragma unroll
    for (int s = 0; s < CS; ++s) a[s] = -__expf(Alog[dd * CS + s]);

    __shared__ float sB[CH][CS];
    __shared__ float sC[CH][CS];
    for (int i = threadIdx.x; i < 2 * CH * CS; i += 256) {
        const int st = i >> 5, j = i & 31;
        const int t = dir ? (CT - 1 - (c * CH + st)) : (c * CH + st);
        const float v = bc[((size_t)b * CT + t) * 32 + j];
        if (j < 16) sB[st][j] = v; else sC[st][j - 16] = v;
    }
    __syncthreads();

    for (int st = 0; st < CH; ++st) {
        const int t = dir ? (CT - 1 - (c * CH + st)) : (c * CH + st);
        const size_t r = (size_t)b * CT + t;
        const float dtv = dt[r * CD + dd];
        const float u   = bf2f(encbf[r * CD + dd]);
        const float du  = dtv * u;
        float acc = 0.f;
        #pragma unroll
        for (int s = 0; s < CS; ++s) {
            const float da = __expf(dtv * a[s]);
            h[s] = fmaf(da, h[s], du * sB[st][s]);
            acc  = fmaf(h[s], sC[st][s], acc);
        }
        ycat[r * 1024 + (size_t)dir * 512 + dd] = f2bf(fmaf(u, dsk, acc));
    }
}

// ---------------- LayerNorm: f32 in -> bf16 out ----------------
__global__ __launch_bounds__(256) void ln_k(const float* __restrict__ h,
                                            short* __restrict__ hbf,
                                            const float* __restrict__ g,
                                            const float* __restrict__ be)
{
    const size_t r = blockIdx.x;
    const int tid = threadIdx.x;
    float2 v = *reinterpret_cast<const float2*>(&h[r * CD + tid * 2]);
    float s  = v.x + v.y;
    float ss = v.x * v.x + v.y * v.y;
    #pragma unroll
    for (int o = 32; o; o >>= 1) { s += __shfl_down(s, o); ss += __shfl_down(ss, o); }
    __shared__ float red[10];
    const int w = tid >> 6;
    if ((tid & 63) == 0) { red[w] = s; red[4 + w] = ss; }
    __syncthreads();
    if (tid == 0) {
        const float S1 = red[0] + red[1] + red[2] + red[3];
        const float S2 = red[4] + red[5] + red[6] + red[7];
        const float mu = S1 / CD;
        red[8] = mu;
        red[9] = rsqrtf(S2 / CD - mu * mu + 1e-5f);
    }
    __syncthreads();
    const float mu = red[8], rs = red[9];
    hbf[r * CD + tid * 2]     = f2bf((v.x - mu) * rs * g[tid * 2]     + be[tid * 2]);
    hbf[r * CD + tid * 2 + 1] = f2bf((v.y - mu) * rs * g[tid * 2 + 1] + be[tid * 2 + 1]);
}

extern "C" void kernel_launch(void* const* d_in, const int* in_sizes, int n_in,
                              void* d_out, int out_size, void* d_ws, size_t ws_size,
                              hipStream_t stream)
{
    const float* x_enc  = (const float*)d_in[0];
    const float* x_mark = (const float*)d_in[1];
    const float* W_emb  = (const float*)d_in[4];
    const float* b_emb  = (const float*)d_in[5];
    const float* Alogf  = (const float*)d_in[6];
    const float* Wxf    = (const float*)d_in[7];
    const float* Wdtf   = (const float*)d_in[8];
    const float* bdtf   = (const float*)d_in[9];
    const float* Dskf   = (const float*)d_in[10];
    const float* Alogb  = (const float*)d_in[11];
    const float* Wxb    = (const float*)d_in[12];
    const float* Wdtb   = (const float*)d_in[13];
    const float* bdtb   = (const float*)d_in[14];
    const float* Dskb   = (const float*)d_in[15];
    const float* Wz     = (const float*)d_in[16];
    const float* bz     = (const float*)d_in[17];
    const float* Wo     = (const float*)d_in[18];
    const float* bo     = (const float*)d_in[19];
    const float* lng    = (const float*)d_in[20];
    const float* lnb    = (const float*)d_in[21];
    const float* Wproj  = (const float*)d_in[22];
    const float* bproj  = (const float*)d_in[23];
    float* out = (float*)d_out;

    float* ws = (float*)d_ws;
    size_t o = 0;
    float* means = ws + o; o += 5136;
    float* stdev = ws + o; o += 5136;
    float* xzf   = ws + o; o += 166400;     // [M][32] Bc|Cc fwd
    float* xzb   = ws + o; o += 166400;
    float* dtf   = ws + o; o += 2662400;
    float* dtb   = ws + o; o += 2662400;
    float* Hloc  = ws + o; o += 3407872;
    float* Pprod = ws + o; o += 3407872;
    short* tokbf = (short*)(ws + o); o += 1331200;   // [5200][512] bf16
    short* encbf = (short*)(ws + o); o += 1331200;
    short* WembT = (short*)(ws + o); o += 131072;
    short* WcatT = (short*)(ws + o); o += 294912;    // [1152][512]
    short* WzT   = (short*)(ws + o); o += 262144;    // [512][1024]
    short* WoT   = (short*)(ws + o); o += 131072;
    short* WpjT  = (short*)(ws + o); o += 24576;     // [96][512]
    float* biascat = ws + o; o += 1152;
    // aliases (lifetime-checked):
    short* ycat    = (short*)Pprod;   // written by scan3 (Pprod dead after scan2)
    short* fusedbf = (short*)Hloc;    // written by G3 (Hloc dead after scan3)
    short* hbf     = tokbf;           // written by ln (tokbf dead after G1)
    float* hb      = dtf;             // written by G4 (dtf dead after scan3)

    stats_k<<<dim3(16, 2), 256, 0, stream>>>(x_enc, means, stdev);
    wprep_k<<<6597, 256, 0, stream>>>(W_emb, Wxf, Wxb, Wdtf, Wdtb, Wz, Wo, Wproj,
                                      bdtf, bdtb, WembT, WcatT, WzT, WoT, WpjT, biascat);
    tok_k<<<dim3(16, 8, 6), 256, 0, stream>>>(x_enc, x_mark, means, stdev, tokbf);

    mgemm_k<M_EMBED><<<dim3(41, 4), 256, 0, stream>>>(
        tokbf, WembT, CM, 512, 512, b_emb, encbf, nullptr, nullptr, nullptr, nullptr, nullptr);

    mgemm_k<M_XZDT><<<dim3(41, 9), 256, 0, stream>>>(
        encbf, WcatT, CM, 1152, 512, biascat, xzf, xzb, dtf, dtb, nullptr, nullptr);

    scan1_k<<<dim3(CB, 2, CNC * 2), 256, 0, stream>>>(
        encbf, xzf, xzb, dtf, dtb, Alogf, Alogb, Hloc, Pprod);
    scan2_k<<<dim3(CB, 2, 32), 256, 0, stream>>>(Hloc, Pprod);
    scan3_k<<<dim3(CB, 2, CNC * 2), 256, 0, stream>>>(
        encbf, xzf, xzb, dtf, dtb, Alogf, Alogb, Dskf, Dskb, Hloc, ycat);

    mgemm_k<M_Z><<<dim3(41, 4), 256, 0, stream>>>(
        ycat, WzT, CM, 512, 1024, bz, fusedbf, nullptr, nullptr, nullptr, ycat, nullptr);

    mgemm_k<M_WO><<<dim3(41, 4), 256, 0, stream>>>(
        fusedbf, WoT, CM, 512, 512, bo, hb, nullptr, nullptr, nullptr, encbf, nullptr);

    ln_k<<<CM, 256, 0, stream>>>(hb, hbf, lng, lnb);

    mgemm_k<M_PROJ><<<dim3(41, 1), 256, 0, stream>>>(
        hbf, WpjT, CM, CPRED, 512, bproj, out, nullptr, nullptr, nullptr, stdev, means);
}

// Round 4
// 230.187 us; speedup vs baseline: 3.1214x; 1.4467x over previous
//
#include <hip/hip_runtime.h>
#include <cstdint>
#include <cstddef>

// ---- problem constants ----
static constexpr int CB   = 16;
static constexpr int CL   = 512;
static constexpr int CN   = 321;
static constexpr int CMK  = 4;
static constexpr int CT   = CN + CMK;  // 325
static constexpr int CD   = 512;
static constexpr int CS   = 16;
static constexpr int CPRED= 96;
static constexpr int CM   = CB * CT;   // 5200
static constexpr int CH   = 25;
static constexpr int CNC  = 13;

typedef short bf16x8 __attribute__((ext_vector_type(8)));
typedef float f32x4  __attribute__((ext_vector_type(4)));

__device__ __forceinline__ float softplus_f(float x) {
    return fmaxf(x, 0.f) + log1pf(__expf(-fabsf(x)));
}
__device__ __forceinline__ short f2bf(float f) {
    uint32_t u = __float_as_uint(f);
    return (short)((u + 0x7fffu + ((u >> 16) & 1u)) >> 16);
}
__device__ __forceinline__ float bf2f(short s) {
    return __uint_as_float(((uint32_t)(uint16_t)s) << 16);
}

// ---------------- stats: parallel over (b, n-tile, l-group) ----------------
__global__ __launch_bounds__(256) void stats_k(const float* __restrict__ x,
                                               float* __restrict__ means,
                                               float* __restrict__ stdev)
{
    const int b  = blockIdx.x;
    const int nn = threadIdx.x & 15;
    const int n  = blockIdx.y * 16 + nn;
    const int lg = threadIdx.x >> 4;
    float s = 0.f, ss = 0.f;
    if (n < CN) {
        #pragma unroll 4
        for (int i = 0; i < 32; ++i) {
            const int l = lg * 32 + i;
            const float v = x[((size_t)b * CL + l) * CN + n];
            s += v; ss += v * v;
        }
    }
    __shared__ float R1[16][17], R2[16][17];
    R1[lg][nn] = s; R2[lg][nn] = ss;
    __syncthreads();
    if (threadIdx.x < 16) {
        float S = 0.f, SS = 0.f;
        #pragma unroll
        for (int g = 0; g < 16; ++g) { S += R1[g][threadIdx.x]; SS += R2[g][threadIdx.x]; }
        const int nf = blockIdx.y * 16 + threadIdx.x;
        if (nf < CN) {
            const float mu = S / CL;
            means[b * CN + nf] = mu;
            stdev[b * CN + nf] = sqrtf(SS / CL - mu * mu + 1e-5f);
        }
    }
}

// ---------------- weight transpose-cast via LDS tiles (coalesced R+W) ----------------
__global__ __launch_bounds__(256) void wtr_k(
    const float* __restrict__ Wemb, const float* __restrict__ Wz,
    const float* __restrict__ Wo,   const float* __restrict__ Wproj,
    const float* __restrict__ Wxf,  const float* __restrict__ Wxb,
    short* __restrict__ WembT, short* __restrict__ WzT, short* __restrict__ WoT,
    short* __restrict__ WpjT,  short* __restrict__ WcatT)
{
    const int bx = blockIdx.x;
    const float* src; short* dst; int R, C, rt, ct;
    if (bx < 64)       { src = Wemb;  dst = WembT; R = 512;  C = 512; rt = bx >> 3;         ct = bx & 7; }
    else if (bx < 192) { src = Wz;    dst = WzT;   R = 1024; C = 512; rt = (bx - 64) >> 3;  ct = (bx - 64) & 7; }
    else if (bx < 256) { src = Wo;    dst = WoT;   R = 512;  C = 512; rt = (bx - 192) >> 3; ct = (bx - 192) & 7; }
    else if (bx < 272) { src = Wproj; dst = WpjT;  R = 512;  C = 96;  rt = (bx - 256) >> 1; ct = (bx - 256) & 1; }
    else if (bx < 280) { src = Wxf;   dst = WcatT; R = 512;  C = 64;  rt = bx - 272;        ct = 0; }
    else               { src = Wxb;   dst = WcatT + (size_t)64 * 512; R = 512; C = 64; rt = bx - 280; ct = 0; }

    __shared__ float S[64][65];
    const int tid = threadIdx.x, tr = tid >> 6, tc = tid & 63;
    const int r0 = rt * 64, c0 = ct * 64;
    #pragma unroll 4
    for (int i = 0; i < 16; ++i) {
        const int rr = i * 4 + tr, gr = r0 + rr, gc = c0 + tc;
        S[rr][tc] = (gr < R && gc < C) ? src[(size_t)gr * C + gc] : 0.f;
    }
    __syncthreads();
    #pragma unroll 4
    for (int i = 0; i < 16; ++i) {
        const int cr = i * 4 + tr, gc = c0 + cr, gr = r0 + tc;
        if (gc < C && gr < R) dst[(size_t)gc * R + gr] = f2bf(S[tc][cr]);
    }
}

// ---------------- Wcomb = Wx[:, :32] @ Wdt  -> WcatT rows (+biascat) ----------------
__global__ __launch_bounds__(256) void wcomb_k(
    const float* __restrict__ Wxf, const float* __restrict__ Wdtf,
    const float* __restrict__ Wxb, const float* __restrict__ Wdtb,
    const float* __restrict__ bdtf, const float* __restrict__ bdtb,
    short* __restrict__ WcatT, float* __restrict__ biascat)
{
    const int bx = blockIdx.x, tid = threadIdx.x;
    if (bx >= 128) {
        const int e = (bx - 128) * 256 + tid;
        if (e < 1152) {
            float v = 0.f;
            if (e >= 640)      v = bdtb[e - 640];
            else if (e >= 128) v = bdtf[e - 128];
            biascat[e] = v;
        }
        return;
    }
    const int dir = bx >> 6, b6 = bx & 63;
    const int kt = b6 >> 3, nt = b6 & 7;
    const float* __restrict__ Wx  = dir ? Wxb  : Wxf;
    const float* __restrict__ Wdt = dir ? Wdtb : Wdtf;
    const int rowbase = dir ? 640 : 128;
    __shared__ float WX[64][33];
    __shared__ float WD[32][65];
    const int k0 = kt * 64, n0 = nt * 64;
    #pragma unroll
    for (int i = 0; i < 8; ++i) {
        const int idx = i * 256 + tid;
        WX[idx >> 5][idx & 31] = Wx[(size_t)(k0 + (idx >> 5)) * 64 + (idx & 31)];
    }
    #pragma unroll
    for (int i = 0; i < 8; ++i) {
        const int idx = i * 256 + tid;
        WD[idx >> 6][idx & 63] = Wdt[(size_t)(idx >> 6) * 512 + n0 + (idx & 63)];
    }
    __syncthreads();
    const int k = tid & 63, nq = tid >> 6;
    float wx[32];
    #pragma unroll
    for (int j = 0; j < 32; ++j) wx[j] = WX[k][j];
    #pragma unroll 4
    for (int nn = 0; nn < 16; ++nn) {
        const int n = nq * 16 + nn;
        float acc = 0.f;
        #pragma unroll
        for (int j = 0; j < 32; ++j) acc = fmaf(wx[j], WD[j][n], acc);
        WcatT[(size_t)(rowbase + n0 + n) * 512 + k0 + k] = f2bf(acc);
    }
}

// ---------------- token build ----------------
__global__ __launch_bounds__(256) void tok_k(const float* __restrict__ xe, const float* __restrict__ xm,
                                             const float* __restrict__ means, const float* __restrict__ stdev,
                                             short* __restrict__ tokbf)
{
    __shared__ float S[64][65];
    const int b = blockIdx.x, l0 = blockIdx.y * 64, t0 = blockIdx.z * 64;
    const int tid = threadIdx.x;
    const int rsub = tid >> 6, c = tid & 63;
    #pragma unroll 4
    for (int i = 0; i < 16; ++i) {
        const int lr = i * 4 + rsub;
        const int t = t0 + c;
        float v = 0.f;
        if (t < CN)      v = xe[((size_t)b * CL + l0 + lr) * CN + t];
        else if (t < CT) v = xm[((size_t)b * CL + l0 + lr) * CMK + (t - CN)];
        S[lr][c] = v;
    }
    __syncthreads();
    #pragma unroll 4
    for (int i = 0; i < 16; ++i) {
        const int tr = i * 4 + rsub;
        const int t = t0 + tr;
        if (t >= CT) continue;
        float v = S[c][tr];
        if (t < CN) v = (v - means[b * CN + t]) / stdev[b * CN + t];
        tokbf[((size_t)b * CT + t) * CL + l0 + c] = f2bf(v);
    }
}

// ---------------- MFMA bf16 GEMM: 128x64 tile, BK=32, double-buffered ----------------
enum GMode { M_EMBED = 0, M_XZDT = 1, M_Z = 2, M_WO = 3, M_PROJ = 4 };

template<int MODE>
__global__ __launch_bounds__(256) void mgemm_k(
    const short* __restrict__ A, const short* __restrict__ Bt,
    int M, int Nmat, int K,
    const float* __restrict__ bias,
    void* __restrict__ o0, void* __restrict__ o1, void* __restrict__ o2, void* __restrict__ o3,
    const void* __restrict__ a0, const void* __restrict__ a1)
{
    constexpr int BM = 128, BN = 64, BK = 32;
    constexpr int LDT = 40;                 // shorts per row (80B: 8 bank-groups over r&7)
    __shared__ short As[2][BM * LDT];       // 2 * 10240 B
    __shared__ short Bs[2][BN * LDT];       // 2 * 5120 B

    const int tid = threadIdx.x;
    const int bm = blockIdx.x * BM, bn = blockIdx.y * BN;
    const int w = tid >> 6, l = tid & 63;
    const int wm = w >> 1, wn = w & 1;      // wave tile: 64m x 32n
    const int lr = l & 15, lk = l >> 4;

    const int am0 = tid >> 2;               // A rows: am0, am0+64
    const int akc = tid & 3;                // 16B chunk within row

    const int nk = K / BK;
    bf16x8 ra0, ra1, rb0;
    const bf16x8 zz = {0,0,0,0,0,0,0,0};

    // tile-0 loads
    {
        const int k = akc * 8;
        const int g0 = bm + am0, g1 = bm + am0 + 64, gb = bn + am0 & 63 ? 0 : 0; // dummy
        ra0 = (g0 < M) ? *reinterpret_cast<const bf16x8*>(&A[(size_t)g0 * K + k]) : zz;
        ra1 = (g1 < M) ? *reinterpret_cast<const bf16x8*>(&A[(size_t)g1 * K + k]) : zz;
        const int gn = bn + (tid >> 2);
        rb0 = (gn < Nmat && am0 < 64) ? *reinterpret_cast<const bf16x8*>(&Bt[(size_t)gn * K + k]) : zz;
    }
    {
        *reinterpret_cast<bf16x8*>(&As[0][am0 * LDT + akc * 8]) = ra0;
        *reinterpret_cast<bf16x8*>(&As[0][(am0 + 64) * LDT + akc * 8]) = ra1;
        if (am0 < 64) *reinterpret_cast<bf16x8*>(&Bs[0][am0 * LDT + akc * 8]) = rb0;
    }
    __syncthreads();

    f32x4 acc[4][2];
    #pragma unroll
    for (int i = 0; i < 4; ++i)
        #pragma unroll
        for (int j = 0; j < 2; ++j) acc[i][j] = (f32x4){0.f, 0.f, 0.f, 0.f};

    for (int t = 0; t < nk; ++t) {
        const int p = t & 1;
        if (t + 1 < nk) {
            const int k = (t + 1) * BK + akc * 8;
            const int g0 = bm + am0, g1 = bm + am0 + 64;
            ra0 = (g0 < M) ? *reinterpret_cast<const bf16x8*>(&A[(size_t)g0 * K + k]) : zz;
            ra1 = (g1 < M) ? *reinterpret_cast<const bf16x8*>(&A[(size_t)g1 * K + k]) : zz;
            const int gn = bn + am0;
            rb0 = (gn < Nmat && am0 < 64) ? *reinterpret_cast<const bf16x8*>(&Bt[(size_t)gn * K + k]) : zz;
        }
        bf16x8 af[4], bg[2];
        #pragma unroll
        for (int f = 0; f < 4; ++f)
            af[f] = *reinterpret_cast<const bf16x8*>(&As[p][(wm * 64 + f * 16 + lr) * LDT + lk * 8]);
        #pragma unroll
        for (int j = 0; j < 2; ++j)
            bg[j] = *reinterpret_cast<const bf16x8*>(&Bs[p][(wn * 32 + j * 16 + lr) * LDT + lk * 8]);
        #pragma unroll
        for (int i = 0; i < 4; ++i)
            #pragma unroll
            for (int j = 0; j < 2; ++j)
                acc[i][j] = __builtin_amdgcn_mfma_f32_16x16x32_bf16(af[i], bg[j], acc[i][j], 0, 0, 0);
        if (t + 1 < nk) {
            *reinterpret_cast<bf16x8*>(&As[p ^ 1][am0 * LDT + akc * 8]) = ra0;
            *reinterpret_cast<bf16x8*>(&As[p ^ 1][(am0 + 64) * LDT + akc * 8]) = ra1;
            if (am0 < 64) *reinterpret_cast<bf16x8*>(&Bs[p ^ 1][am0 * LDT + akc * 8]) = rb0;
        }
        __syncthreads();
    }

    // epilogue: C/D frag layout col = lane&15, row = (lane>>4)*4 + reg
    #pragma unroll
    for (int i = 0; i < 4; ++i) {
        #pragma unroll
        for (int r = 0; r < 4; ++r) {
            const int rr = bm + wm * 64 + i * 16 + lk * 4 + r;
            if (rr >= M) continue;
            #pragma unroll
            for (int j = 0; j < 2; ++j) {
                const int cc = bn + wn * 32 + j * 16 + lr;
                float v = acc[i][j][r];
                if constexpr (MODE == M_EMBED) {
                    v += bias[cc];
                    ((short*)o0)[(size_t)rr * 512 + cc] = f2bf(v);
                } else if constexpr (MODE == M_XZDT) {
                    v += bias[cc];
                    if (cc < 32) { }
                    else if (cc < 64)  ((float*)o0)[(size_t)rr * 32 + cc - 32] = v;
                    else if (cc < 96)  { }
                    else if (cc < 128) ((float*)o1)[(size_t)rr * 32 + cc - 96] = v;
                    else if (cc < 640) ((float*)o2)[(size_t)rr * 512 + cc - 128] = softplus_f(v);
                    else               ((float*)o3)[(size_t)rr * 512 + cc - 640] = softplus_f(v);
                } else if constexpr (MODE == M_Z) {
                    v += bias[cc];
                    const float z  = 1.f / (1.f + __expf(-v));
                    const short* yc = (const short*)a0;
                    const float yf = bf2f(yc[(size_t)rr * 1024 + cc]);
                    const float yb = bf2f(yc[(size_t)rr * 1024 + 512 + cc]);
                    ((short*)o0)[(size_t)rr * 512 + cc] = f2bf(z * yf + (1.f - z) * yb);
                } else if constexpr (MODE == M_WO) {
                    v += bias[cc] + bf2f(((const short*)a0)[(size_t)rr * 512 + cc]);
                    ((float*)o0)[(size_t)rr * 512 + cc] = v;
                } else if constexpr (MODE == M_PROJ) {
                    if (cc >= CPRED) continue;
                    const int pb = rr / CT, pt = rr % CT;
                    if (pt >= CN) continue;
                    v += bias[cc];
                    const float sc = ((const float*)a0)[pb * CN + pt];
                    const float sh = ((const float*)a1)[pb * CN + pt];
                    ((float*)o0)[(size_t)pb * (CPRED * CN) + (size_t)cc * CN + pt] = v * sc + sh;
                }
            }
        }
    }
}

// ---------------- chunked selective scan ----------------
__global__ __launch_bounds__(256) void scan1_k(
    const short* __restrict__ encbf,
    const float* __restrict__ bcf, const float* __restrict__ bcb,
    const float* __restrict__ dtf, const float* __restrict__ dtb,
    const float* __restrict__ Alogf, const float* __restrict__ Alogb,
    float* __restrict__ Hloc, float* __restrict__ Pprod)
{
    const int b   = blockIdx.x;
    const int dir = blockIdx.y;
    const int c   = blockIdx.z >> 1;
    const int dd  = (blockIdx.z & 1) * 256 + threadIdx.x;

    const float* __restrict__ bc   = dir ? bcb : bcf;
    const float* __restrict__ dt   = dir ? dtb : dtf;
    const float* __restrict__ Alog = dir ? Alogb : Alogf;

    float a[CS], h[CS], P[CS];
    #pragma unroll
    for (int s = 0; s < CS; ++s) {
        a[s] = -__expf(Alog[dd * CS + s]);
        h[s] = 0.f; P[s] = 1.f;
    }

    __shared__ float sB[CH][CS];
    for (int i = threadIdx.x; i < CH * CS; i += 256) {
        const int st = i >> 4, j = i & 15;
        const int t = dir ? (CT - 1 - (c * CH + st)) : (c * CH + st);
        sB[st][j] = bc[((size_t)b * CT + t) * 32 + j];
    }
    __syncthreads();

    for (int st = 0; st < CH; ++st) {
        const int t = dir ? (CT - 1 - (c * CH + st)) : (c * CH + st);
        const size_t r = (size_t)b * CT + t;
        const float dtv = dt[r * CD + dd];
        const float du  = dtv * bf2f(encbf[r * CD + dd]);
        #pragma unroll
        for (int s = 0; s < CS; ++s) {
            const float da = __expf(dtv * a[s]);
            h[s] = fmaf(da, h[s], du * sB[st][s]);
            P[s] *= da;
        }
    }

    const size_t o = ((((size_t)b * 2 + dir) * CNC + c) * CD + dd) * CS;
    float4* Ho = reinterpret_cast<float4*>(&Hloc[o]);
    float4* Po = reinterpret_cast<float4*>(&Pprod[o]);
    #pragma unroll
    for (int q = 0; q < 4; ++q) {
        Ho[q] = make_float4(h[4*q], h[4*q+1], h[4*q+2], h[4*q+3]);
        Po[q] = make_float4(P[4*q], P[4*q+1], P[4*q+2], P[4*q+3]);
    }
}

__global__ __launch_bounds__(256) void scan2_k(float* __restrict__ Hloc,
                                               const float* __restrict__ Pprod)
{
    const int b   = blockIdx.x;
    const int dir = blockIdx.y;
    const int d   = blockIdx.z * 16 + (threadIdx.x >> 4);
    const int s   = threadIdx.x & 15;
    const size_t base = ((size_t)b * 2 + dir) * CNC * CD * CS + (size_t)d * CS + s;
    float H = 0.f;
    for (int c = 0; c < CNC; ++c) {
        const size_t o = base + (size_t)c * CD * CS;
        const float p  = Pprod[o];
        const float hl = Hloc[o];
        Hloc[o] = H;
        H = fmaf(p, H, hl);
    }
}

__global__ __launch_bounds__(256) void scan3_k(
    const short* __restrict__ encbf,
    const float* __restrict__ bcf, const float* __restrict__ bcb,
    const float* __restrict__ dtf, const float* __restrict__ dtb,
    const float* __restrict__ Alogf, const float* __restrict__ Alogb,
    const float* __restrict__ Dskf, const float* __restrict__ Dskb,
    const float* __restrict__ Hinit,
    short* __restrict__ ycat)
{
    const int b   = blockIdx.x;
    const int dir = blockIdx.y;
    const int c   = blockIdx.z >> 1;
    const int dd  = (blockIdx.z & 1) * 256 + threadIdx.x;

    const float* __restrict__ bc   = dir ? bcb : bcf;
    const float* __restrict__ dt   = dir ? dtb : dtf;
    const float* __restrict__ Alog = dir ? Alogb : Alogf;
    const float dsk = (dir ? Dskb : Dskf)[dd];

    float a[CS], h[CS];
    const size_t o = ((((size_t)b * 2 + dir) * CNC + c) * CD + dd) * CS;
    const float4* Hi = reinterpret_cast<const float4*>(&Hinit[o]);
    #pragma unroll
    for (int q = 0; q < 4; ++q) {
        const float4 v = Hi[q];
        h[4*q] = v.x; h[4*q+1] = v.y; h[4*q+2] = v.z; h[4*q+3] = v.w;
    }
    #pragma unroll
    for (int s = 0; s < CS; ++s) a[s] = -__expf(Alog[dd * CS + s]);

    __shared__ float sB[CH][CS];
    __shared__ float sC[CH][CS];
    for (int i = threadIdx.x; i < 2 * CH * CS; i += 256) {
        const int st = i >> 5, j = i & 31;
        const int t = dir ? (CT - 1 - (c * CH + st)) : (c * CH + st);
        const float v = bc[((size_t)b * CT + t) * 32 + j];
        if (j < 16) sB[st][j] = v; else sC[st][j - 16] = v;
    }
    __syncthreads();

    for (int st = 0; st < CH; ++st) {
        const int t = dir ? (CT - 1 - (c * CH + st)) : (c * CH + st);
        const size_t r = (size_t)b * CT + t;
        const float dtv = dt[r * CD + dd];
        const float u   = bf2f(encbf[r * CD + dd]);
        const float du  = dtv * u;
        float acc = 0.f;
        #pragma unroll
        for (int s = 0; s < CS; ++s) {
            const float da = __expf(dtv * a[s]);
            h[s] = fmaf(da, h[s], du * sB[st][s]);
            acc  = fmaf(h[s], sC[st][s], acc);
        }
        ycat[r * 1024 + (size_t)dir * 512 + dd] = f2bf(fmaf(u, dsk, acc));
    }
}

// ---------------- LayerNorm: f32 in -> bf16 out ----------------
__global__ __launch_bounds__(256) void ln_k(const float* __restrict__ h,
                                            short* __restrict__ hbf,
                                            const float* __restrict__ g,
                                            const float* __restrict__ be)
{
    const size_t r = blockIdx.x;
    const int tid = threadIdx.x;
    float2 v = *reinterpret_cast<const float2*>(&h[r * CD + tid * 2]);
    float s  = v.x + v.y;
    float ss = v.x * v.x + v.y * v.y;
    #pragma unroll
    for (int o = 32; o; o >>= 1) { s += __shfl_down(s, o); ss += __shfl_down(ss, o); }
    __shared__ float red[10];
    const int w = tid >> 6;
    if ((tid & 63) == 0) { red[w] = s; red[4 + w] = ss; }
    __syncthreads();
    if (tid == 0) {
        const float S1 = red[0] + red[1] + red[2] + red[3];
        const float S2 = red[4] + red[5] + red[6] + red[7];
        const float mu = S1 / CD;
        red[8] = mu;
        red[9] = rsqrtf(S2 / CD - mu * mu + 1e-5f);
    }
    __syncthreads();
    const float mu = red[8], rs = red[9];
    hbf[r * CD + tid * 2]     = f2bf((v.x - mu) * rs * g[tid * 2]     + be[tid * 2]);
    hbf[r * CD + tid * 2 + 1] = f2bf((v.y - mu) * rs * g[tid * 2 + 1] + be[tid * 2 + 1]);
}

extern "C" void kernel_launch(void* const* d_in, const int* in_sizes, int n_in,
                              void* d_out, int out_size, void* d_ws, size_t ws_size,
                              hipStream_t stream)
{
    const float* x_enc  = (const float*)d_in[0];
    const float* x_mark = (const float*)d_in[1];
    const float* W_emb  = (const float*)d_in[4];
    const float* b_emb  = (const float*)d_in[5];
    const float* Alogf  = (const float*)d_in[6];
    const float* Wxf    = (const float*)d_in[7];
    const float* Wdtf   = (const float*)d_in[8];
    const float* bdtf   = (const float*)d_in[9];
    const float* Dskf   = (const float*)d_in[10];
    const float* Alogb  = (const float*)d_in[11];
    const float* Wxb    = (const float*)d_in[12];
    const float* Wdtb   = (const float*)d_in[13];
    const float* bdtb   = (const float*)d_in[14];
    const float* Dskb   = (const float*)d_in[15];
    const float* Wz     = (const float*)d_in[16];
    const float* bz     = (const float*)d_in[17];
    const float* Wo     = (const float*)d_in[18];
    const float* bo     = (const float*)d_in[19];
    const float* lng    = (const float*)d_in[20];
    const float* lnb    = (const float*)d_in[21];
    const float* Wproj  = (const float*)d_in[22];
    const float* bproj  = (const float*)d_in[23];
    float* out = (float*)d_out;

    float* ws = (float*)d_ws;
    size_t o = 0;
    float* means = ws + o; o += 5136;
    float* stdev = ws + o; o += 5136;
    float* xzf   = ws + o; o += 166400;     // [M][32] Bc|Cc fwd
    float* xzb   = ws + o; o += 166400;
    float* dtf   = ws + o; o += 2662400;
    float* dtb   = ws + o; o += 2662400;
    float* Hloc  = ws + o; o += 3407872;
    float* Pprod = ws + o; o += 3407872;
    short* tokbf = (short*)(ws + o); o += 1331200;   // [5200][512] bf16
    short* encbf = (short*)(ws + o); o += 1331200;
    short* WembT = (short*)(ws + o); o += 131072;
    short* WcatT = (short*)(ws + o); o += 294912;    // [1152][512]
    short* WzT   = (short*)(ws + o); o += 262144;    // [512][1024]
    short* WoT   = (short*)(ws + o); o += 131072;
    short* WpjT  = (short*)(ws + o); o += 24576;     // [96][512]
    float* biascat = ws + o; o += 1152;
    // aliases (lifetime-checked):
    short* ycat    = (short*)Pprod;   // written by scan3 (Pprod dead after scan2)
    short* fusedbf = (short*)Hloc;    // written by Z-gemm (Hloc dead after scan3)
    short* hbf     = tokbf;           // written by ln (tokbf dead after EMBED)
    float* hb      = dtf;             // written by WO-gemm (dtf dead after scan3)

    stats_k<<<dim3(16, 21), 256, 0, stream>>>(x_enc, means, stdev);
    wtr_k<<<288, 256, 0, stream>>>(W_emb, Wz, Wo, Wproj, Wxf, Wxb,
                                   WembT, WzT, WoT, WpjT, WcatT);
    wcomb_k<<<133, 256, 0, stream>>>(Wxf, Wdtf, Wxb, Wdtb, bdtf, bdtb, WcatT, biascat);
    tok_k<<<dim3(16, 8, 6), 256, 0, stream>>>(x_enc, x_mark, means, stdev, tokbf);

    mgemm_k<M_EMBED><<<dim3(41, 8), 256, 0, stream>>>(
        tokbf, WembT, CM, 512, 512, b_emb, encbf, nullptr, nullptr, nullptr, nullptr, nullptr);

    mgemm_k<M_XZDT><<<dim3(41, 18), 256, 0, stream>>>(
        encbf, WcatT, CM, 1152, 512, biascat, xzf, xzb, dtf, dtb, nullptr, nullptr);

    scan1_k<<<dim3(CB, 2, CNC * 2), 256, 0, stream>>>(
        encbf, xzf, xzb, dtf, dtb, Alogf, Alogb, Hloc, Pprod);
    scan2_k<<<dim3(CB, 2, 32), 256, 0, stream>>>(Hloc, Pprod);
    scan3_k<<<dim3(CB, 2, CNC * 2), 256, 0, stream>>>(
        encbf, xzf, xzb, dtf, dtb, Alogf, Alogb, Dskf, Dskb, Hloc, ycat);

    mgemm_k<M_Z><<<dim3(41, 8), 256, 0, stream>>>(
        ycat, WzT, CM, 512, 1024, bz, fusedbf, nullptr, nullptr, nullptr, ycat, nullptr);

    mgemm_k<M_WO><<<dim3(41, 8), 256, 0, stream>>>(
        fusedbf, WoT, CM, 512, 512, bo, hb, nullptr, nullptr, nullptr, encbf, nullptr);

    ln_k<<<CM, 256, 0, stream>>>(hb, hbf, lng, lnb);

    mgemm_k<M_PROJ><<<dim3(41, 2), 256, 0, stream>>>(
        hbf, WpjT, CM, CPRED, 512, bproj, out, nullptr, nullptr, nullptr, stdev, means);
}